// Round 18
// baseline (94.565 us; speedup 1.0000x reference)
//
#include <hip/hip_runtime.h>

// Problem constants: B=16, TQ=256, TK=256, QD=512, KD=512
// d_out = [ tanh_out: 16*256*512 f32 ; p: 16*256*256 f32 ]
// scores[b,q,k] = (sum_n w_n + b_att) - 2 * sum_n w_n / (1 + Ea[q,n]*Ek[k,n])
//   Ea = exp2(C2*aq), Ek = exp2(C2*keys), C2 = 2*log2(e)
// R18: GEMMs get 2-DEEP register prefetch (two named sets, even/odd unroll;
// loads land ~2 compute phases ahead of their ds_write -> vmcnt stall gone).
// Everything else identical to R17 (94.4us).

#define C2 2.88539008177792681f

typedef unsigned short u16;
typedef short s16x8 __attribute__((ext_vector_type(8)));
typedef float f32x4 __attribute__((ext_vector_type(4)));

__device__ __forceinline__ float fast_rcp(float x) { return __builtin_amdgcn_rcpf(x); }

__device__ __forceinline__ u16 f2bf(float f) {
  union { float f; unsigned u; } v; v.f = f;
  unsigned r = v.u + 0x7fffu + ((v.u >> 16) & 1u);
  return (u16)(r >> 16);
}
__device__ __forceinline__ unsigned packbf(float a, float b) {
  return (unsigned)f2bf(a) | ((unsigned)f2bf(b) << 16);
}

// ---------------------------------------------------------------------------
// Mega-prep, one launch (3841 blocks):
//  [0,2048):     keys tile -> Ek (fp32 exp2, straight) + kbfT (bf16, transposed)
//  [2048,3072):  qbf = bf16(query)
//  [3072,3840):  Wqt / Woutt = bf16(W^T)
//  3840:         Cptr = sum(w_att) + b_att
// ---------------------------------------------------------------------------
__global__ __launch_bounds__(256) void mega_prep(
    const float* __restrict__ keys, float* __restrict__ Ek,
    const float* __restrict__ query, u16* __restrict__ qbf,
    u16* __restrict__ kbfT,
    const float* __restrict__ Wq, u16* __restrict__ Wqt,
    const float* __restrict__ Wout, u16* __restrict__ Woutt,
    const float* __restrict__ w_att, const float* __restrict__ b_att,
    float* __restrict__ Cptr)
{
  __shared__ float red[4];
  __shared__ u16 tile[32][40];
  const int t = threadIdx.x;
  const int bx = blockIdx.x;

  if (bx < 2048) {
    const int b = bx >> 7, rem = bx & 127;
    const int k0 = (rem >> 4) * 32, n0 = (rem & 15) * 32;
    const float* src = keys + (size_t)b * 131072;
    const int r = t >> 3, c = (t & 7) * 4;
    const size_t off = (size_t)(k0 + r) * 512 + n0 + c;
    float4 v = *(const float4*)&src[off];
    float4 o;
    o.x = exp2f(C2 * v.x); o.y = exp2f(C2 * v.y);
    o.z = exp2f(C2 * v.z); o.w = exp2f(C2 * v.w);
    *(float4*)&Ek[(size_t)b * 131072 + off] = o;
    tile[c + 0][r] = f2bf(v.x); tile[c + 1][r] = f2bf(v.y);
    tile[c + 2][r] = f2bf(v.z); tile[c + 3][r] = f2bf(v.w);
    __syncthreads();
    if (t < 128) {
      const int row = t >> 2, ch = (t & 3) * 8;
      unsigned p0 = (unsigned)tile[row][ch + 0] | ((unsigned)tile[row][ch + 1] << 16);
      unsigned p1 = (unsigned)tile[row][ch + 2] | ((unsigned)tile[row][ch + 3] << 16);
      unsigned p2 = (unsigned)tile[row][ch + 4] | ((unsigned)tile[row][ch + 5] << 16);
      unsigned p3 = (unsigned)tile[row][ch + 6] | ((unsigned)tile[row][ch + 7] << 16);
      *(int4*)&kbfT[(size_t)b * 131072 + (size_t)(n0 + row) * 256 + k0 + ch] =
          make_int4(p0, p1, p2, p3);
    }
  } else if (bx < 3072) {
    const size_t i8 = ((size_t)(bx - 2048) * 256 + t) * 8;
    float4 a = *(const float4*)&query[i8];
    float4 b = *(const float4*)&query[i8 + 4];
    unsigned p0 = packbf(a.x, a.y), p1 = packbf(a.z, a.w);
    unsigned p2 = packbf(b.x, b.y), p3 = packbf(b.z, b.w);
    *(int4*)&qbf[i8] = make_int4(p0, p1, p2, p3);
  } else if (bx < 3840) {
    const int b3 = bx - 3072;
    const int by = b3 >> 4;
    const int n0 = (b3 & 15) * 32;
    const float* W; u16* Wt; int K, k0;
    if (by < 16) { W = Wq;   Wt = Wqt;   K = 512;  k0 = by * 32; }
    else         { W = Wout; Wt = Woutt; K = 1024; k0 = (by - 16) * 32; }
    const int r = t >> 3, c = (t & 7) * 4;
    float4 v = *(const float4*)&W[(size_t)(k0 + r) * 512 + n0 + c];
    tile[c + 0][r] = f2bf(v.x); tile[c + 1][r] = f2bf(v.y);
    tile[c + 2][r] = f2bf(v.z); tile[c + 3][r] = f2bf(v.w);
    __syncthreads();
    if (t < 128) {
      const int row = t >> 2, ch = (t & 3) * 8;
      unsigned p0 = (unsigned)tile[row][ch + 0] | ((unsigned)tile[row][ch + 1] << 16);
      unsigned p1 = (unsigned)tile[row][ch + 2] | ((unsigned)tile[row][ch + 3] << 16);
      unsigned p2 = (unsigned)tile[row][ch + 4] | ((unsigned)tile[row][ch + 5] << 16);
      unsigned p3 = (unsigned)tile[row][ch + 6] | ((unsigned)tile[row][ch + 7] << 16);
      *(int4*)&Wt[(size_t)(n0 + row) * K + k0 + ch] = make_int4(p0, p1, p2, p3);
    }
  } else {
    float wsum = w_att[t] + w_att[t + 256];
#pragma unroll
    for (int m = 32; m; m >>= 1) wsum += __shfl_xor(wsum, m);
    if ((t & 63) == 0) red[t >> 6] = wsum;
    __syncthreads();
    if (t == 0) Cptr[0] = red[0] + red[1] + red[2] + red[3] + b_att[0];
  }
}

// ---------------------------------------------------------------------------
// K1/K4: bf16 MFMA GEMM, BK=64, 2-DEEP register prefetch. Tile 64x64, 4 waves.
// LDS rows 72 elems (144B): 2-way banks (free). XCD swizzle (8,64 grid).
// Loop unrolled x2 with named prefetch sets A/B (static indexing, rule #20).
// nIter must be even and >= 2 (K=512 -> 8, K=1024 -> 16).
// ---------------------------------------------------------------------------
__global__ __launch_bounds__(256) void gemm_mfma_bf16(
    const u16* __restrict__ A0, const u16* __restrict__ A1, int kSplit,
    const u16* __restrict__ Bt, const float* __restrict__ bias,
    float* __restrict__ C, int K, int act)
{
  __shared__ u16 As[64 * 72];
  __shared__ u16 Bs[64 * 72];
  const int t = threadIdx.x;
  const int lane = t & 63, wid = t >> 6;
  const int wm = wid >> 1, wn = wid & 1;
  const int f = blockIdx.x + blockIdx.y * 8;
  const int w = (f & 63) * 8 + (f >> 6);
  const int col0 = (w & 7) * 64, row0 = (w >> 3) * 64;
  const int lr = t >> 2, lc = (t & 3) * 16;
  const int fr = lane & 15, fg = (lane >> 4) * 8;

  f32x4 acc[2][2] = {};
  const int nIter = K >> 6;

#define GLOAD(aset0, aset1, bset0, bset1, k0_) { \
    const u16* Asrc_; int kc_; \
    if ((k0_) < kSplit) { Asrc_ = A0; kc_ = (k0_); } \
    else { Asrc_ = A1; kc_ = (k0_) - kSplit; } \
    aset0 = *(const int4*)&Asrc_[(size_t)(row0 + lr) * 512 + kc_ + lc]; \
    aset1 = *(const int4*)&Asrc_[(size_t)(row0 + lr) * 512 + kc_ + lc + 8]; \
    bset0 = *(const int4*)&Bt[(size_t)(col0 + lr) * K + (k0_) + lc]; \
    bset1 = *(const int4*)&Bt[(size_t)(col0 + lr) * K + (k0_) + lc + 8]; }

#define STAGE_COMPUTE(aset0, aset1, bset0, bset1) { \
    __syncthreads(); \
    *(int4*)&As[lr * 72 + lc]     = aset0; \
    *(int4*)&As[lr * 72 + lc + 8] = aset1; \
    *(int4*)&Bs[lr * 72 + lc]     = bset0; \
    *(int4*)&Bs[lr * 72 + lc + 8] = bset1; \
    __syncthreads(); }

#define MFMA_PHASE() { \
    _Pragma("unroll") \
    for (int ks = 0; ks < 2; ++ks) { \
      s16x8 af[2], bfr[2]; \
      _Pragma("unroll") \
      for (int m = 0; m < 2; ++m) \
        af[m] = *(const s16x8*)&As[(wm * 32 + m * 16 + fr) * 72 + ks * 32 + fg]; \
      _Pragma("unroll") \
      for (int n = 0; n < 2; ++n) \
        bfr[n] = *(const s16x8*)&Bs[(wn * 32 + n * 16 + fr) * 72 + ks * 32 + fg]; \
      _Pragma("unroll") \
      for (int m = 0; m < 2; ++m) \
        _Pragma("unroll") \
        for (int n = 0; n < 2; ++n) \
          acc[m][n] = __builtin_amdgcn_mfma_f32_16x16x32_bf16(af[m], bfr[n], acc[m][n], 0, 0, 0); \
    } }

  int4 a0A, a1A, b0A, b1A;  // even-iter set
  int4 a0B, a1B, b0B, b1B;  // odd-iter set
  GLOAD(a0A, a1A, b0A, b1A, 0);
  GLOAD(a0B, a1B, b0B, b1B, 64);

  for (int it = 0; it < nIter; it += 2) {
    // even iter: stage set A, refill A with it+2, compute
    STAGE_COMPUTE(a0A, a1A, b0A, b1A);
    if (it + 2 < nIter) GLOAD(a0A, a1A, b0A, b1A, (it + 2) << 6);
    MFMA_PHASE();
    // odd iter: stage set B, refill B with it+3, compute
    STAGE_COMPUTE(a0B, a1B, b0B, b1B);
    if (it + 3 < nIter) GLOAD(a0B, a1B, b0B, b1B, (it + 3) << 6);
    MFMA_PHASE();
  }
#undef GLOAD
#undef STAGE_COMPUTE
#undef MFMA_PHASE

  const int fq = lane >> 4;
#pragma unroll
  for (int n = 0; n < 2; ++n) {
    const int col = col0 + wn * 32 + n * 16 + fr;
    const float bv = bias[col];
#pragma unroll
    for (int m = 0; m < 2; ++m) {
#pragma unroll
      for (int i = 0; i < 4; ++i) {
        const int row = row0 + wm * 32 + m * 16 + fq * 4 + i;
        float v = acc[m][n][i] + bv;
        if (act == 1) {
          float e = __expf(2.0f * v);
          v = 1.0f - 2.0f * fast_rcp(e + 1.0f);
        } else if (act == 2) {
          v = exp2f(C2 * v);
        }
        C[(size_t)row * 512 + col] = v;
      }
    }
  }
}

// ---------------------------------------------------------------------------
// K2: partial scores over an n-QUARTER (128). grid (4,4,64). FROZEN (R16).
// ---------------------------------------------------------------------------
__global__ __launch_bounds__(256) void score_kernel(
    const float* __restrict__ Ea, const float* __restrict__ Ek,
    const float* __restrict__ w_att, const float* __restrict__ Cptr,
    float* __restrict__ S)
{
  __shared__ float ek_s[64][68];

  const int z = blockIdx.z;
  const int b = z >> 2, qt = z & 3;
  const int q0 = blockIdx.y * 64, k0 = blockIdx.x * 64;
  const int t = threadIdx.x;

  const int qi = t >> 4, ki = t & 15;
  const int lr = t >> 2, lc = (t & 3) * 16;
  const float* eaq = Ea + (size_t)(b * 256 + q0 + qi) * 512 + qt * 128;
  const float* ekp = Ek + (size_t)(b * 256 + k0) * 512 + qt * 128;
  const float* wbase = w_att + qt * 128;

  float acc[4][4] = {};

#define TERM4(a4, kv, wv, accv) { \
    float q1 = fmaf(a4.x, kv.x, 1.0f); \
    float q2 = fmaf(a4.y, kv.y, 1.0f); \
    float q3 = fmaf(a4.z, kv.z, 1.0f); \
    float q4 = fmaf(a4.w, kv.w, 1.0f); \
    float N12 = fmaf(wv.x, q2, wv.y * q1); \
    float D12 = q1 * q2; \
    float N34 = fmaf(wv.z, q4, wv.w * q3); \
    float D34 = q3 * q4; \
    float Nt = fmaf(N12, D34, N34 * D12); \
    float Dt = D12 * D34; \
    accv = fmaf(Nt, fast_rcp(Dt), accv); }

  for (int c = 0; c < 2; ++c) {
    const int gb = lr * 512 + c * 64 + lc;
    float4 K0 = *(const float4*)&ekp[gb + 0];
    float4 K1 = *(const float4*)&ekp[gb + 4];
    float4 K2 = *(const float4*)&ekp[gb + 8];
    float4 K3 = *(const float4*)&ekp[gb + 12];
    __syncthreads();
    *(float4*)&ek_s[lr][lc + 0]  = K0;
    *(float4*)&ek_s[lr][lc + 4]  = K1;
    *(float4*)&ek_s[lr][lc + 8]  = K2;
    *(float4*)&ek_s[lr][lc + 12] = K3;
    __syncthreads();

    for (int j = 0; j < 64; j += 8) {
      const float* wq = wbase + c * 64 + j;
      float4 wv0 = *(const float4*)&wq[0];
      float4 wv1 = *(const float4*)&wq[4];
      float4 kv0[4], kv1[4];
#pragma unroll
      for (int n = 0; n < 4; ++n) {
        kv0[n] = *(const float4*)&ek_s[ki + n * 16][j];
        kv1[n] = *(const float4*)&ek_s[ki + n * 16][j + 4];
      }
#pragma unroll
      for (int m = 0; m < 4; ++m) {
        float4 av0 = *(const float4*)&eaq[m * 16 * 512 + c * 64 + j];
        float4 av1 = *(const float4*)&eaq[m * 16 * 512 + c * 64 + j + 4];
#pragma unroll
        for (int n = 0; n < 4; ++n) {
          TERM4(av0, kv0[n], wv0, acc[m][n]);
          TERM4(av1, kv1[n], wv1, acc[m][n]);
        }
      }
    }
  }
#undef TERM4

  const float Cv = (qt == 0) ? Cptr[0] : 0.0f;
  float* sc = S + (size_t)qt * 1048576;
#pragma unroll
  for (int m = 0; m < 4; ++m) {
    const size_t qr = (size_t)(b * 256 + q0 + qi + m * 16);
#pragma unroll
    for (int n = 0; n < 4; ++n)
      sc[qr * 256 + k0 + ki + n * 16] = fmaf(-2.f, acc[m][n], Cv);
  }
}

// ---------------------------------------------------------------------------
// K3a: softmax-only. One wave per q-row; writes p_out (f32) and pbf (bf16).
// ---------------------------------------------------------------------------
__global__ __launch_bounds__(256) void softmax_kernel(
    const float* __restrict__ S, float* __restrict__ p_out,
    u16* __restrict__ pbf)
{
  const int t = threadIdx.x;
  const int w = t >> 6, lane = t & 63;
  const int row = blockIdx.x * 4 + w;
  const size_t off = (size_t)row * 256 + lane * 4;
  float4 sa = *(const float4*)&S[off];
  float4 sb = *(const float4*)&S[off + 1048576];
  float4 sc = *(const float4*)&S[off + 2097152];
  float4 sd = *(const float4*)&S[off + 3145728];
  float4 s4 = {(sa.x + sb.x) + (sc.x + sd.x), (sa.y + sb.y) + (sc.y + sd.y),
               (sa.z + sb.z) + (sc.z + sd.z), (sa.w + sb.w) + (sc.w + sd.w)};
  float m = fmaxf(fmaxf(s4.x, s4.y), fmaxf(s4.z, s4.w));
#pragma unroll
  for (int msk = 32; msk; msk >>= 1) m = fmaxf(m, __shfl_xor(m, msk));
  float e0 = __expf(s4.x - m);
  float e1 = __expf(s4.y - m);
  float e2 = __expf(s4.z - m);
  float e3 = __expf(s4.w - m);
  float ssum = (e0 + e1) + (e2 + e3);
#pragma unroll
  for (int msk = 32; msk; msk >>= 1) ssum += __shfl_xor(ssum, msk);
  float rs = 1.0f / ssum;
  float4 p4 = {e0 * rs, e1 * rs, e2 * rs, e3 * rs};
  *(float4*)&p_out[off] = p4;
  unsigned lo = packbf(p4.x, p4.y), hi = packbf(p4.z, p4.w);
  *(int2*)&pbf[off] = make_int2(lo, hi);
}

// ---------------------------------------------------------------------------
// K3b: ctx(bf16) = pbf @ kbfT per batch. MFMA, tile 64x64, BK=64, K=256.
// XCD swizzle within z-slice; 2-deep prefetch (4 iters: preload 0,1).
// ---------------------------------------------------------------------------
__global__ __launch_bounds__(256) void ctx_gemm(
    const u16* __restrict__ pbf, const u16* __restrict__ kbfT,
    u16* __restrict__ ctxbf)
{
  __shared__ u16 As[64 * 72];
  __shared__ u16 Bs[64 * 72];
  const int t = threadIdx.x;
  const int lane = t & 63, wid = t >> 6;
  const int wm = wid >> 1, wn = wid & 1;
  const int f = blockIdx.x + blockIdx.y * 8;
  const int w = (f & 3) * 8 + (f >> 2);
  const int col0 = (w & 7) * 64, row0 = (w >> 3) * 64, b = blockIdx.z;
  const u16* A = pbf + (size_t)b * 65536;
  const u16* Bm = kbfT + (size_t)b * 131072;
  const int lr = t >> 2, lc = (t & 3) * 16;
  const int fr = lane & 15, fg = (lane >> 4) * 8;

  f32x4 acc[2][2] = {};

#define GLOADC(aset0, aset1, bset0, bset1, k0_) { \
    aset0 = *(const int4*)&A[(size_t)(row0 + lr) * 256 + (k0_) + lc]; \
    aset1 = *(const int4*)&A[(size_t)(row0 + lr) * 256 + (k0_) + lc + 8]; \
    bset0 = *(const int4*)&Bm[(size_t)(col0 + lr) * 256 + (k0_) + lc]; \
    bset1 = *(const int4*)&Bm[(size_t)(col0 + lr) * 256 + (k0_) + lc + 8]; }

#define STAGE_COMPUTEC(aset0, aset1, bset0, bset1) { \
    __syncthreads(); \
    *(int4*)&As[lr * 72 + lc]     = aset0; \
    *(int4*)&As[lr * 72 + lc + 8] = aset1; \
    *(int4*)&Bs[lr * 72 + lc]     = bset0; \
    *(int4*)&Bs[lr * 72 + lc + 8] = bset1; \
    __syncthreads(); }

#define MFMA_PHASEC() { \
    _Pragma("unroll") \
    for (int ks = 0; ks < 2; ++ks) { \
      s16x8 af[2], bfr[2]; \
      _Pragma("unroll") \
      for (int m = 0; m < 2; ++m) \
        af[m] = *(const s16x8*)&As[(wm * 32 + m * 16 + fr) * 72 + ks * 32 + fg]; \
      _Pragma("unroll") \
      for (int n = 0; n < 2; ++n) \
        bfr[n] = *(const s16x8*)&Bs[(wn * 32 + n * 16 + fr) * 72 + ks * 32 + fg]; \
      _Pragma("unroll") \
      for (int m = 0; m < 2; ++m) \
        _Pragma("unroll") \
        for (int n = 0; n < 2; ++n) \
          acc[m][n] = __builtin_amdgcn_mfma_f32_16x16x32_bf16(af[m], bfr[n], acc[m][n], 0, 0, 0); \
    } }

  int4 a0A, a1A, b0A, b1A;
  int4 a0B, a1B, b0B, b1B;
  GLOADC(a0A, a1A, b0A, b1A, 0);
  GLOADC(a0B, a1B, b0B, b1B, 64);

  for (int it = 0; it < 4; it += 2) {
    STAGE_COMPUTEC(a0A, a1A, b0A, b1A);
    if (it + 2 < 4) GLOADC(a0A, a1A, b0A, b1A, (it + 2) << 6);
    MFMA_PHASEC();
    STAGE_COMPUTEC(a0B, a1B, b0B, b1B);
    if (it + 3 < 4) GLOADC(a0B, a1B, b0B, b1B, (it + 3) << 6);
    MFMA_PHASEC();
  }
#undef GLOADC
#undef STAGE_COMPUTEC
#undef MFMA_PHASEC

  const int fq = lane >> 4;
#pragma unroll
  for (int n = 0; n < 2; ++n) {
    const int col = col0 + wn * 32 + n * 16 + fr;
#pragma unroll
    for (int m = 0; m < 2; ++m) {
#pragma unroll
      for (int i = 0; i < 4; ++i) {
        const int row = row0 + wm * 32 + m * 16 + fq * 4 + i;
        ctxbf[(size_t)(b * 256 + row) * 512 + col] = f2bf(acc[m][n][i]);
      }
    }
  }
}

// ---------------------------------------------------------------------------
extern "C" void kernel_launch(void* const* d_in, const int* in_sizes, int n_in,
                              void* d_out, int out_size, void* d_ws, size_t ws_size,
                              hipStream_t stream) {
  const float* query = (const float*)d_in[0];
  const float* keys  = (const float*)d_in[1];
  const float* Wq    = (const float*)d_in[2];
  const float* bq    = (const float*)d_in[3];
  const float* w_att = (const float*)d_in[4];
  const float* b_att = (const float*)d_in[5];
  const float* Wout  = (const float*)d_in[6];
  const float* bout  = (const float*)d_in[7];

  float* out_tanh = (float*)d_out;                  // [4096][512]
  float* out_p    = out_tanh + (size_t)4096 * 512;  // [4096][256]

  float* ws = (float*)d_ws;
  float* Ea     = ws;                    // [4096][512] f32 (dead after K2)
  float* Ek     = ws + 2097152;          // [4096][512] f32 (dead after K2)
  float* S      = ws + 4194304;          // [4][4096][256] f32 (dead after K3a)
  float* Cptr   = ws + 8388608;          // [1] (+pad to 16)
  u16*   Wqt    = (u16*)(ws + 8388624);  // [512][512] bf16
  u16*   Woutt  = Wqt + 262144;          // [512][1024] bf16
  u16*   qbf    = Woutt + 524288;        // [4096][512] bf16
  u16*   kbfT   = qbf + 2097152;         // [16][512][256] bf16
  u16*   pbf    = kbfT + 2097152;        // [16][256][256] bf16
  u16*   ctxbf  = (u16*)Ea;              // [4096][512] bf16, aliases dead Ea

  // One fused prep launch: Ek+kbfT (keys read once), qbf, Wqt/Woutt, Cptr
  mega_prep<<<3841, 256, 0, stream>>>(
      keys, Ek, query, qbf, kbfT, Wq, Wqt, Wout, Woutt, w_att, b_att, Cptr);

  // K1: Ea = exp2(C2 * (qbf @ Wq + bq))   [MFMA bf16, 2-deep prefetch]
  gemm_mfma_bf16<<<dim3(8, 64), 256, 0, stream>>>(
      qbf, qbf, 512, Wqt, bq, Ea, 512, 2);

  // K2: partial scores (4 n-quarters) [frozen]
  score_kernel<<<dim3(4, 4, 64), 256, 0, stream>>>(
      Ea, Ek, w_att, Cptr, S);

  // K3a: softmax (writes p fp32 + pbf bf16)
  softmax_kernel<<<1024, 256, 0, stream>>>(S, out_p, pbf);

  // K3b: ctxbf = pbf @ kbfT   [batched MFMA bf16, 2-deep prefetch]
  ctx_gemm<<<dim3(8, 4, 16), 256, 0, stream>>>(pbf, kbfT, ctxbf);

  // K4: out = tanh(concat(qbf, ctxbf) @ Wout + bout)   [MFMA bf16, 2-deep]
  gemm_mfma_bf16<<<dim3(8, 64), 256, 0, stream>>>(
      qbf, ctxbf, 512, Woutt, bout, out_tanh, 1024, 1);
}